// Round 10
// baseline (352.627 us; speedup 1.0000x reference)
//
#include <hip/hip_runtime.h>

#define S_LEN 4096
#define D_DIM 64
#define NBH   64   // B*H = 4*16
#define EPS_F 1e-6f
#define PSZ   (D_DIM * D_DIM + D_DIM)   // 4160 floats per block partial (KV + ksum)

__device__ __forceinline__ float phi_f(float x) {
    // elu(x)+1 == x>0 ? x+1 : exp(x)
    return x > 0.0f ? x + 1.0f : __expf(x);
}

// ---------------------------------------------------------------------------
// Mask dtype detector (see round-1 notes): classifies bool buffer encoding.
// ---------------------------------------------------------------------------
__global__ void detect_mask(const unsigned int* __restrict__ w,
                            unsigned int* __restrict__ flag) {
    __shared__ int all01, allf;
    if (threadIdx.x == 0) { all01 = 1; allf = 1; }
    __syncthreads();
    int a = 1, f = 1;
    for (int i = threadIdx.x; i < 4096; i += blockDim.x) {
        unsigned int v = w[i];
        if (v > 1u) a = 0;
        if (v != 0u && v != 0x3F800000u) f = 0;
    }
    if (!a) atomicExch(&all01, 0);
    if (!f) atomicExch(&allf, 0);
    __syncthreads();
    if (threadIdx.x == 0) *flag = all01 ? 0u : (allf ? 2u : 1u);
}

// ---------------------------------------------------------------------------
// Phase 1 (round-10 rewrite): GLOBAL-DIRECT, no LDS staging, no main-loop
// barriers. Theory: rounds 3/9 proved the 8-way-broadcast ds_read_b128
// pattern costs ~4x (84us vs 21us floors, invariant to barrier count).
// Global broadcast loads are dedup'd by the coalescer; TLP (4 waves/SIMD)
// hides HBM latency. Mask: 64 rows preloaded per-lane, __shfl per row.
// Epilogue (cross-wave LDS reduce + partial store) kept from round 9.
// ---------------------------------------------------------------------------
__global__ __launch_bounds__(256) void la_phase1(
    const float* __restrict__ K, const float* __restrict__ V,
    const void* __restrict__ mask, const unsigned int* __restrict__ flagp,
    float* __restrict__ partials, int CH)
{
    __shared__ float red[4096];
    __shared__ float ksred[4][64];

    const int bh   = blockIdx.x;
    const int b    = bh >> 4;             // H = 16
    const unsigned int flag = *flagp;
    const int tid  = threadIdx.x;
    const int wave = tid >> 6;
    const int lane = tid & 63;
    const int tt   = lane >> 3;           // d-octet
    const int tf   = lane & 7;            // f-octet
    const int chunk = S_LEN / CH;         // rows per block
    const int rpw   = chunk >> 2;         // rows per wave (contiguous)
    const int s0    = blockIdx.y * chunk + wave * rpw;

    const float* Kr = K + ((size_t)bh * S_LEN + s0) * D_DIM;
    const float* Vr = V + ((size_t)bh * S_LEN + s0) * D_DIM;
    const int*           mi = (const int*)mask;
    const unsigned char* mb = (const unsigned char*)mask;
    const float*         mf = (const float*)mask;
    const int ml0 = b * S_LEN + s0;

    float acc[8][8];
    float ks[8];
    #pragma unroll
    for (int i = 0; i < 8; ++i) {
        ks[i] = 0.0f;
        #pragma unroll
        for (int j = 0; j < 8; ++j) acc[i][j] = 0.0f;
    }

    for (int seg = 0; seg < rpw; seg += 64) {
        // one coalesced mask load per 64 rows; per-row broadcast via shfl
        int mvi;
        {
            const int ml = ml0 + seg + lane;
            if (flag == 0u)      mvi = (mi[ml] != 0);
            else if (flag == 1u) mvi = (mb[ml] != 0);
            else                 mvi = (mf[ml] != 0.0f);
        }
        const float* Ks = Kr + (size_t)seg * D_DIM;
        const float* Vs = Vr + (size_t)seg * D_DIM;
        #pragma unroll 2
        for (int r = 0; r < 64; ++r) {
            const int pad = __shfl(mvi, r);
            float kk[8], vv[8];
            *reinterpret_cast<float4*>(&kk[0]) = *reinterpret_cast<const float4*>(Ks + r * 64 + tt * 8);
            *reinterpret_cast<float4*>(&kk[4]) = *reinterpret_cast<const float4*>(Ks + r * 64 + tt * 8 + 4);
            *reinterpret_cast<float4*>(&vv[0]) = *reinterpret_cast<const float4*>(Vs + r * 64 + tf * 8);
            *reinterpret_cast<float4*>(&vv[4]) = *reinterpret_cast<const float4*>(Vs + r * 64 + tf * 8 + 4);
            // zeroing K alone suffices: k*v = 0 and ksum uses masked k
            #pragma unroll
            for (int i = 0; i < 8; ++i)
                kk[i] = pad ? 0.0f : phi_f(kk[i]);
            #pragma unroll
            for (int i = 0; i < 8; ++i) {
                #pragma unroll
                for (int j = 0; j < 8; ++j)
                    acc[i][j] = fmaf(kk[i], vv[j], acc[i][j]);
                ks[i] += kk[i];
            }
        }
    }

    // ---- cross-wave reduction through LDS, then one coalesced store ----
    if (tf == 0) {
        #pragma unroll
        for (int i = 0; i < 8; ++i) ksred[wave][tt * 8 + i] = ks[i];
    }
    __syncthreads();
    for (int w = 0; w < 4; ++w) {
        if (wave == w) {
            #pragma unroll
            for (int i = 0; i < 8; ++i) {
                float4* p0 = reinterpret_cast<float4*>(&red[(tt * 8 + i) * 64 + tf * 8]);
                float4 a0 = make_float4(acc[i][0], acc[i][1], acc[i][2], acc[i][3]);
                float4 a1 = make_float4(acc[i][4], acc[i][5], acc[i][6], acc[i][7]);
                if (w == 0) { p0[0] = a0; p0[1] = a1; }
                else {
                    float4 c0 = p0[0], c1 = p0[1];
                    c0.x += a0.x; c0.y += a0.y; c0.z += a0.z; c0.w += a0.w;
                    c1.x += a1.x; c1.y += a1.y; c1.z += a1.z; c1.w += a1.w;
                    p0[0] = c0; p0[1] = c1;
                }
            }
        }
        __syncthreads();
    }

    float* pp = partials + ((size_t)(bh * CH + blockIdx.y)) * PSZ;
    #pragma unroll
    for (int q = 0; q < 4; ++q) {
        int fi = q * 256 + tid;           // float4 idx 0..1023
        reinterpret_cast<float4*>(pp)[fi] = reinterpret_cast<const float4*>(red)[fi];
    }
    if (tid < 64)
        pp[4096 + tid] = ksred[0][tid] + ksred[1][tid] + ksred[2][tid] + ksred[3][tid];
}

// ---------------------------------------------------------------------------
// Reduce CH partials per bh into final KV (64x64) and ksum (64).
// (Round-8 coverage bug fixed in round 9 — verified passing.)
// ---------------------------------------------------------------------------
template <int CHT>
__global__ __launch_bounds__(256) void la_reduce_t(
    const float* __restrict__ partials, float* __restrict__ kv,
    float* __restrict__ ksum)
{
    const int bh = blockIdx.x;
    const int half = blockIdx.y;                 // 0..1, each covers 520 f4
    const float4* base = reinterpret_cast<const float4*>(partials + (size_t)bh * CHT * PSZ);
    const int hi = (half + 1) * 520;             // PSZ/4 = 1040 total
    for (int idx = half * 520 + threadIdx.x; idx < hi; idx += 256) {
        float4 s = make_float4(0.f, 0.f, 0.f, 0.f);
        #pragma unroll
        for (int c = 0; c < CHT; ++c) {
            float4 v = base[(size_t)c * (PSZ / 4) + idx];
            s.x += v.x; s.y += v.y; s.z += v.z; s.w += v.w;
        }
        if (idx < 1024)
            reinterpret_cast<float4*>(kv + (size_t)bh * 4096)[idx] = s;
        else
            reinterpret_cast<float4*>(ksum + bh * 64)[idx - 1024] = s;
    }
}

// ---------------------------------------------------------------------------
// Phase 2 (round-10 rewrite): NO LDS at all. KV (16KB/bh) is read directly
// from global — L1-resident per CU after first touch; the old kvs LDS reads
// were the same 8-way-broadcast ds_read_b128 pattern as phase1 (~4x cost).
// ksum loads are lane-uniform -> scalarized by compiler. No barriers.
// Block 256 = 4 waves, each wave 32 t rows, 4t x 8f per lane.
// ---------------------------------------------------------------------------
__global__ __launch_bounds__(256) void la_phase2(
    const float* __restrict__ Q,
    const float* __restrict__ kv_ws, const float* __restrict__ ksum_ws,
    float* __restrict__ out)
{
    const int bh   = blockIdx.x;
    const int tid  = threadIdx.x;     // 0..255
    const int wave = tid >> 6;
    const int lane = tid & 63;
    const int tt   = lane >> 3;       // t-phase (0..7)
    const int tf   = lane & 7;        // f-octet
    const int t0   = blockIdx.y * 128 + wave * 32;   // wave's rows: t0+tt+8r

    const float* qr0 = Q + ((size_t)bh * S_LEN + t0 + tt) * D_DIM;
    const float* kvb = kv_ws + (size_t)bh * D_DIM * D_DIM;
    const float* ksb = ksum_ws + bh * D_DIM;

    float acc[4][8];
    float z[4];
    #pragma unroll
    for (int r = 0; r < 4; ++r) {
        z[r] = 0.0f;
        #pragma unroll
        for (int c = 0; c < 8; ++c) acc[r][c] = 0.0f;
    }

    #pragma unroll 2
    for (int dq = 0; dq < 64; dq += 4) {
        float ks4[4];
        *reinterpret_cast<float4*>(ks4) = *reinterpret_cast<const float4*>(ksb + dq); // uniform -> SGPR
        float qc[4][4];
        #pragma unroll
        for (int r = 0; r < 4; ++r) {
            float4 q4 = *reinterpret_cast<const float4*>(qr0 + r * 8 * D_DIM + dq);
            qc[r][0] = phi_f(q4.x); qc[r][1] = phi_f(q4.y);
            qc[r][2] = phi_f(q4.z); qc[r][3] = phi_f(q4.w);
        }
        #pragma unroll
        for (int j = 0; j < 4; ++j) {
            float kvr[8];
            *reinterpret_cast<float4*>(&kvr[0]) = *reinterpret_cast<const float4*>(kvb + (dq + j) * 64 + tf * 8);
            *reinterpret_cast<float4*>(&kvr[4]) = *reinterpret_cast<const float4*>(kvb + (dq + j) * 64 + tf * 8 + 4);
            #pragma unroll
            for (int r = 0; r < 4; ++r) {
                z[r] = fmaf(qc[r][j], ks4[j], z[r]);
                #pragma unroll
                for (int c = 0; c < 8; ++c)
                    acc[r][c] = fmaf(qc[r][j], kvr[c], acc[r][c]);
            }
        }
    }

    #pragma unroll
    for (int r = 0; r < 4; ++r) {
        int t = t0 + tt + 8 * r;
        float inv = 1.0f / (z[r] + EPS_F);
        float o[8];
        #pragma unroll
        for (int c = 0; c < 8; ++c) o[c] = acc[r][c] * inv;
        float* op = out + ((size_t)bh * S_LEN + t) * D_DIM + tf * 8;
        *reinterpret_cast<float4*>(&op[0]) = *reinterpret_cast<const float4*>(&o[0]);
        *reinterpret_cast<float4*>(&op[4]) = *reinterpret_cast<const float4*>(&o[4]);
    }
}

// ---------------------------------------------------------------------------
extern "C" void kernel_launch(void* const* d_in, const int* in_sizes, int n_in,
                              void* d_out, int out_size, void* d_ws, size_t ws_size,
                              hipStream_t stream)
{
    (void)in_sizes; (void)n_in; (void)out_size;
    const float* Q   = (const float*)d_in[0];
    const float* K   = (const float*)d_in[1];
    const float* V   = (const float*)d_in[2];
    const void* mask = d_in[3];

    // ws layout: partials[NBH*CH*PSZ] | kv[NBH*4096] | ksum[NBH*64] | flag
    int CH = 16;
    while (CH > 1) {
        size_t need = ((size_t)NBH * CH * PSZ + (size_t)NBH * 4096 + NBH * 64) * 4 + 16;
        if (need <= ws_size) break;
        CH >>= 1;
    }
    float* partials = (float*)d_ws;
    float* kvf  = partials + (size_t)NBH * CH * PSZ;
    float* ksf  = kvf + (size_t)NBH * 4096;
    unsigned int* flag = (unsigned int*)(ksf + NBH * 64);

    detect_mask<<<1, 256, 0, stream>>>((const unsigned int*)mask, flag);
    la_phase1<<<dim3(NBH, CH), 256, 0, stream>>>(K, V, mask, flag, partials, CH);
    switch (CH) {
        case 16: la_reduce_t<16><<<dim3(NBH, 2), 256, 0, stream>>>(partials, kvf, ksf); break;
        case 8:  la_reduce_t<8> <<<dim3(NBH, 2), 256, 0, stream>>>(partials, kvf, ksf); break;
        case 4:  la_reduce_t<4> <<<dim3(NBH, 2), 256, 0, stream>>>(partials, kvf, ksf); break;
        case 2:  la_reduce_t<2> <<<dim3(NBH, 2), 256, 0, stream>>>(partials, kvf, ksf); break;
        default: la_reduce_t<1> <<<dim3(NBH, 2), 256, 0, stream>>>(partials, kvf, ksf); break;
    }
    la_phase2<<<dim3(NBH, 32), 256, 0, stream>>>(Q, kvf, ksf, (float*)d_out);
}

// Round 11
// 291.902 us; speedup vs baseline: 1.2080x; 1.2080x over previous
//
#include <hip/hip_runtime.h>

#define S_LEN 4096
#define D_DIM 64
#define NBH   64   // B*H = 4*16
#define EPS_F 1e-6f
#define PSZ   (D_DIM * D_DIM + D_DIM)   // 4160 floats per block partial (KV + ksum)

__device__ __forceinline__ float phi_f(float x) {
    // elu(x)+1 == x>0 ? x+1 : exp(x)
    return x > 0.0f ? x + 1.0f : __expf(x);
}

// ---------------------------------------------------------------------------
// Mask dtype detector (see round-1 notes): classifies bool buffer encoding.
// ---------------------------------------------------------------------------
__global__ void detect_mask(const unsigned int* __restrict__ w,
                            unsigned int* __restrict__ flag) {
    __shared__ int all01, allf;
    if (threadIdx.x == 0) { all01 = 1; allf = 1; }
    __syncthreads();
    int a = 1, f = 1;
    for (int i = threadIdx.x; i < 4096; i += blockDim.x) {
        unsigned int v = w[i];
        if (v > 1u) a = 0;
        if (v != 0u && v != 0x3F800000u) f = 0;
    }
    if (!a) atomicExch(&all01, 0);
    if (!f) atomicExch(&allf, 0);
    __syncthreads();
    if (threadIdx.x == 0) *flag = all01 ? 0u : (allf ? 2u : 1u);
}

// ---------------------------------------------------------------------------
// Phase 1 (round-11): 8-wave blocks, 4d x 8f lane tile (acc 32 VGPR, was 64)
// -> target ~6 waves/SIMD resident (was 4). Double-buffered LDS, one barrier
// per 32-row tile, register prefetch — round-9 proven pipeline. Mask staged
// per-tile in LDS, applied as broadcast multiply in compute.
// Wave w: rq = w>>1 picks 8 rows of the tile, dh = w&1 picks d-half.
// ---------------------------------------------------------------------------
__global__ __launch_bounds__(512) void la_phase1(
    const float* __restrict__ K, const float* __restrict__ V,
    const void* __restrict__ mask, const unsigned int* __restrict__ flagp,
    float* __restrict__ partials, int CH)
{
    __shared__ float smem[2][4096];   // [buf][ k:0..2048 | v:2048..4096 ]
    __shared__ float mlds[2][32];     // [buf][tile row] = 0 (pad) / 1 (valid)
    __shared__ float ksred[4][64];

    const int bh   = blockIdx.x;
    const int b    = bh >> 4;             // H = 16
    const unsigned int flag = *flagp;
    const int tid  = threadIdx.x;         // 0..511
    const int wv   = tid >> 6;            // 0..7
    const int lane = tid & 63;
    const int rq   = wv >> 1;             // row quarter (8 rows of 32)
    const int dh   = wv & 1;              // d half (0: d0-31, 1: d32-63)
    const int dgrp = lane >> 3;           // 0..7 -> d = dh*32 + dgrp*4 + i
    const int fgrp = lane & 7;            // f = fgrp*8 + j
    const int chunk = S_LEN / CH;
    const int NT    = chunk / 32;
    const int s0    = blockIdx.y * chunk;

    const float* Kbh = K + (size_t)bh * S_LEN * D_DIM;
    const float* Vbh = V + (size_t)bh * S_LEN * D_DIM;
    const int*           mi = (const int*)mask;
    const unsigned char* mb = (const unsigned char*)mask;
    const float*         mf = (const float*)mask;

    float acc[4][8];
    float ks[4];
    #pragma unroll
    for (int i = 0; i < 4; ++i) {
        ks[i] = 0.0f;
        #pragma unroll
        for (int j = 0; j < 8; ++j) acc[i][j] = 0.0f;
    }

    const int srow = tid >> 4;            // 0..31 (one f4 per thread per array)
    const int scol = (tid & 15) * 4;

    float4 kr, vr;
    float  mreg = 1.0f;

    auto issue = [&](int ts) {
        const int s = s0 + ts + srow;
        kr = *reinterpret_cast<const float4*>(&Kbh[(size_t)s * D_DIM + scol]);
        vr = *reinterpret_cast<const float4*>(&Vbh[(size_t)s * D_DIM + scol]);
        if (tid < 32) {
            const int ml = b * S_LEN + s0 + ts + tid;
            bool pad;
            if (flag == 0u)      pad = (mi[ml] != 0);
            else if (flag == 1u) pad = (mb[ml] != 0);
            else                 pad = (mf[ml] != 0.0f);
            mreg = pad ? 0.0f : 1.0f;
        }
    };

    auto xstore = [&](int bufi) {
        float4 k4 = kr;
        k4.x = phi_f(k4.x); k4.y = phi_f(k4.y);
        k4.z = phi_f(k4.z); k4.w = phi_f(k4.w);
        *reinterpret_cast<float4*>(&smem[bufi][srow * 64 + scol])        = k4;
        *reinterpret_cast<float4*>(&smem[bufi][2048 + srow * 64 + scol]) = vr;
        if (tid < 32) mlds[bufi][tid] = mreg;
    };

    issue(0);
    xstore(0);
    __syncthreads();
    int cur = 0;
    for (int it = 0; it < NT; ++it) {
        if (it + 1 < NT) issue((it + 1) * 32);
        const float* kb = &smem[cur][(rq * 8) * 64 + dh * 32 + dgrp * 4];
        const float* vb = &smem[cur][2048 + (rq * 8) * 64 + fgrp * 8];
        const float* mp = &mlds[cur][rq * 8];
        #pragma unroll
        for (int r = 0; r < 8; ++r) {
            const float m = mp[r];                 // LDS broadcast
            float kk[4], vv[8];
            *reinterpret_cast<float4*>(&kk[0]) = *reinterpret_cast<const float4*>(kb + r * 64);
            *reinterpret_cast<float4*>(&vv[0]) = *reinterpret_cast<const float4*>(vb + r * 64);
            *reinterpret_cast<float4*>(&vv[4]) = *reinterpret_cast<const float4*>(vb + r * 64 + 4);
            #pragma unroll
            for (int i = 0; i < 4; ++i) kk[i] *= m;  // pad row -> 0 (kv & ksum)
            #pragma unroll
            for (int i = 0; i < 4; ++i) {
                #pragma unroll
                for (int j = 0; j < 8; ++j)
                    acc[i][j] = fmaf(kk[i], vv[j], acc[i][j]);
                ks[i] += kk[i];
            }
        }
        if (it + 1 < NT) xstore(cur ^ 1);
        __syncthreads();
        cur ^= 1;
    }

    // ---- cross-wave reduction: ksum, then KV into red (= smem[0]) ----
    if (fgrp == 0) {
        #pragma unroll
        for (int i = 0; i < 4; ++i)
            ksred[rq][dh * 32 + dgrp * 4 + i] = ks[i];
    }
    __syncthreads();      // all compute done; safe to reuse smem[0] as red

    float* red = smem[0];
    for (int q = 0; q < 4; ++q) {
        if (rq == q) {    // both d-halves write disjoint rows concurrently
            #pragma unroll
            for (int i = 0; i < 4; ++i) {
                float4* p0 = reinterpret_cast<float4*>(
                    &red[(dh * 32 + dgrp * 4 + i) * 64 + fgrp * 8]);
                float4 a0 = make_float4(acc[i][0], acc[i][1], acc[i][2], acc[i][3]);
                float4 a1 = make_float4(acc[i][4], acc[i][5], acc[i][6], acc[i][7]);
                if (q == 0) { p0[0] = a0; p0[1] = a1; }
                else {
                    float4 c0 = p0[0], c1 = p0[1];
                    c0.x += a0.x; c0.y += a0.y; c0.z += a0.z; c0.w += a0.w;
                    c1.x += a1.x; c1.y += a1.y; c1.z += a1.z; c1.w += a1.w;
                    p0[0] = c0; p0[1] = c1;
                }
            }
        }
        __syncthreads();
    }

    float* pp = partials + ((size_t)(bh * CH + blockIdx.y)) * PSZ;
    #pragma unroll
    for (int q = 0; q < 2; ++q) {
        int fi = q * 512 + tid;           // float4 idx 0..1023
        reinterpret_cast<float4*>(pp)[fi] = reinterpret_cast<const float4*>(red)[fi];
    }
    if (tid < 64)
        pp[4096 + tid] = ksred[0][tid] + ksred[1][tid] + ksred[2][tid] + ksred[3][tid];
}

// ---------------------------------------------------------------------------
// Reduce CH partials per bh into final KV (64x64) and ksum (64).
// (Coverage-verified in round 9.)
// ---------------------------------------------------------------------------
template <int CHT>
__global__ __launch_bounds__(256) void la_reduce_t(
    const float* __restrict__ partials, float* __restrict__ kv,
    float* __restrict__ ksum)
{
    const int bh = blockIdx.x;
    const int half = blockIdx.y;                 // 0..1, each covers 520 f4
    const float4* base = reinterpret_cast<const float4*>(partials + (size_t)bh * CHT * PSZ);
    const int hi = (half + 1) * 520;             // PSZ/4 = 1040 total
    for (int idx = half * 520 + threadIdx.x; idx < hi; idx += 256) {
        float4 s = make_float4(0.f, 0.f, 0.f, 0.f);
        #pragma unroll
        for (int c = 0; c < CHT; ++c) {
            float4 v = base[(size_t)c * (PSZ / 4) + idx];
            s.x += v.x; s.y += v.y; s.z += v.z; s.w += v.w;
        }
        if (idx < 1024)
            reinterpret_cast<float4*>(kv + (size_t)bh * 4096)[idx] = s;
        else
            reinterpret_cast<float4*>(ksum + bh * 64)[idx - 1024] = s;
    }
}

// ---------------------------------------------------------------------------
// Phase 2 (round-11): round-9 structure (KV+ksum in LDS, q global-direct)
// + TWO-group-deep q register prefetch (8 loads in flight, ~640cy cover for
// the ~900cy HBM miss — was 1-deep/~320cy, the round-9/10 stall source).
// Block 256 = 4 waves, each wave 32 t rows, 4t x 8f per lane.
// ---------------------------------------------------------------------------
__global__ __launch_bounds__(256) void la_phase2(
    const float* __restrict__ Q,
    const float* __restrict__ kv_ws, const float* __restrict__ ksum_ws,
    float* __restrict__ out)
{
    __shared__ float kvs[64][64];     // [d][f]
    __shared__ float kss[64];

    const int bh   = blockIdx.x;
    const int tid  = threadIdx.x;     // 0..255
    const int wave = tid >> 6;
    const int lane = tid & 63;
    const int tt   = lane >> 3;       // t-phase (0..7)
    const int tf   = lane & 7;        // f-octet
    const int t0   = blockIdx.y * 128 + wave * 32;   // wave's rows: t0+tt+8r

    const float* Qbh = Q + (size_t)bh * S_LEN * D_DIM;
    const float* kvb = kv_ws + (size_t)bh * D_DIM * D_DIM;

    // stage KV (4096 floats) + ksum
    #pragma unroll
    for (int p = 0; p < 4; ++p) {
        int fi = p * 256 + tid;       // float4 idx 0..1023
        reinterpret_cast<float4*>(kvs)[fi] = reinterpret_cast<const float4*>(kvb)[fi];
    }
    if (tid < 16)
        reinterpret_cast<float4*>(kss)[tid] =
            reinterpret_cast<const float4*>(ksum_ws + bh * D_DIM)[tid];
    __syncthreads();

    const float* qr0 = Qbh + (size_t)(t0 + tt) * D_DIM;   // row r at +r*8*64

    float acc[4][8];
    float z[4];
    #pragma unroll
    for (int r = 0; r < 4; ++r) {
        z[r] = 0.0f;
        #pragma unroll
        for (int c = 0; c < 8; ++c) acc[r][c] = 0.0f;
    }

    float4 qn0[4], qn1[4];            // 2-deep prefetch pipeline
    #pragma unroll
    for (int r = 0; r < 4; ++r) {
        qn0[r] = *reinterpret_cast<const float4*>(qr0 + r * 8 * D_DIM);
        qn1[r] = *reinterpret_cast<const float4*>(qr0 + r * 8 * D_DIM + 4);
    }

    #pragma unroll
    for (int dq = 0; dq < 64; dq += 4) {
        float qc[4][4];
        #pragma unroll
        for (int r = 0; r < 4; ++r) {
            qc[r][0] = phi_f(qn0[r].x); qc[r][1] = phi_f(qn0[r].y);
            qc[r][2] = phi_f(qn0[r].z); qc[r][3] = phi_f(qn0[r].w);
            qn0[r] = qn1[r];
        }
        const int dnext = (dq + 8) & 63;   // wraps: in-bounds, unused on tail
        #pragma unroll
        for (int r = 0; r < 4; ++r)
            qn1[r] = *reinterpret_cast<const float4*>(qr0 + r * 8 * D_DIM + dnext);
        float ks4[4];
        *reinterpret_cast<float4*>(ks4) = *reinterpret_cast<const float4*>(&kss[dq]);
        #pragma unroll
        for (int j = 0; j < 4; ++j) {
            float kvr[8];
            *reinterpret_cast<float4*>(&kvr[0]) = *reinterpret_cast<const float4*>(&kvs[dq + j][tf * 8]);
            *reinterpret_cast<float4*>(&kvr[4]) = *reinterpret_cast<const float4*>(&kvs[dq + j][tf * 8 + 4]);
            #pragma unroll
            for (int r = 0; r < 4; ++r) {
                z[r] = fmaf(qc[r][j], ks4[j], z[r]);
                #pragma unroll
                for (int c = 0; c < 8; ++c)
                    acc[r][c] = fmaf(qc[r][j], kvr[c], acc[r][c]);
            }
        }
    }

    #pragma unroll
    for (int r = 0; r < 4; ++r) {
        int t = t0 + tt + 8 * r;
        float inv = 1.0f / (z[r] + EPS_F);
        float o[8];
        #pragma unroll
        for (int c = 0; c < 8; ++c) o[c] = acc[r][c] * inv;
        float* op = out + ((size_t)bh * S_LEN + t) * D_DIM + tf * 8;
        *reinterpret_cast<float4*>(&op[0]) = *reinterpret_cast<const float4*>(&o[0]);
        *reinterpret_cast<float4*>(&op[4]) = *reinterpret_cast<const float4*>(&o[4]);
    }
}

// ---------------------------------------------------------------------------
extern "C" void kernel_launch(void* const* d_in, const int* in_sizes, int n_in,
                              void* d_out, int out_size, void* d_ws, size_t ws_size,
                              hipStream_t stream)
{
    (void)in_sizes; (void)n_in; (void)out_size;
    const float* Q   = (const float*)d_in[0];
    const float* K   = (const float*)d_in[1];
    const float* V   = (const float*)d_in[2];
    const void* mask = d_in[3];

    // ws layout: partials[NBH*CH*PSZ] | kv[NBH*4096] | ksum[NBH*64] | flag
    int CH = 16;
    while (CH > 1) {
        size_t need = ((size_t)NBH * CH * PSZ + (size_t)NBH * 4096 + NBH * 64) * 4 + 16;
        if (need <= ws_size) break;
        CH >>= 1;
    }
    float* partials = (float*)d_ws;
    float* kvf  = partials + (size_t)NBH * CH * PSZ;
    float* ksf  = kvf + (size_t)NBH * 4096;
    unsigned int* flag = (unsigned int*)(ksf + NBH * 64);

    detect_mask<<<1, 256, 0, stream>>>((const unsigned int*)mask, flag);
    la_phase1<<<dim3(NBH, CH), 512, 0, stream>>>(K, V, mask, flag, partials, CH);
    switch (CH) {
        case 16: la_reduce_t<16><<<dim3(NBH, 2), 256, 0, stream>>>(partials, kvf, ksf); break;
        case 8:  la_reduce_t<8> <<<dim3(NBH, 2), 256, 0, stream>>>(partials, kvf, ksf); break;
        case 4:  la_reduce_t<4> <<<dim3(NBH, 2), 256, 0, stream>>>(partials, kvf, ksf); break;
        case 2:  la_reduce_t<2> <<<dim3(NBH, 2), 256, 0, stream>>>(partials, kvf, ksf); break;
        default: la_reduce_t<1> <<<dim3(NBH, 2), 256, 0, stream>>>(partials, kvf, ksf); break;
    }
    la_phase2<<<dim3(NBH, 32), 256, 0, stream>>>(Q, kvf, ksf, (float*)d_out);
}